// Round 8
// baseline (150.587 us; speedup 1.0000x reference)
//
#include <hip/hip_runtime.h>
#include <hip/hip_bf16.h>

// Problem: CrossViewFusionModule
//   global_query: [B=16, D=256] f32
//   value:        [B=16, D=256, W=128, H=128] f32
//   q = l2norm(q, axis=-1); v = l2norm(value, axis=D)
//   score[b,wh] = sum_d q[b,d]*v[b,d,wh]
//   attn = (score - min_b) / (max_b - min_b + 1e-8)   (min/max over wh per b)
//   context = attn * v
//   outputs: (context [B,D,W,H], attn [B,1,W,H]) concat in d_out.
//
// R8: phase-split by batch. Two score->ctx kernel pairs, 8 b's each.
// Per-phase value working set = 134 MB << 256 MB L3, so the ctx pass's
// re-read of value is served from Infinity Cache (R6's counters proved
// cache-served re-reads: FETCH=251 MB for a double-read workload).
// 256 blocks/kernel (grid 32x8), float2/thread. nt stores for ctx/attn.

#define B_  16
#define D_  256
#define WH_ 16384   // 128*128
#define PHB 8       // batches per phase

// ---- monotone float <-> sortable uint mapping (for exact atomic min/max) ----
__device__ __forceinline__ unsigned int fmap(float f) {
    unsigned int u = __float_as_uint(f);
    return (u & 0x80000000u) ? ~u : (u | 0x80000000u);
}
__device__ __forceinline__ float funmap(unsigned int u) {
    unsigned int b = (u & 0x80000000u) ? (u ^ 0x80000000u) : ~u;
    return __uint_as_float(b);
}

typedef float f32x2_t __attribute__((ext_vector_type(2)));
__device__ __forceinline__ void nt_store2(float* p, float a, float b) {
    f32x2_t w = {a, b};
    __builtin_nontemporal_store(w, (f32x2_t*)p);   // global_store_dwordx2 ... nt
}

__global__ void init_mm_kernel(unsigned int* __restrict__ mm) {
    int i = threadIdx.x;
    if (i < 2 * B_) mm[i] = (i & 1) ? 0u : 0xFFFFFFFFu;  // even: min, odd: max
}

// grid = (32, PHB), block = 256. Each thread: one float2 wh-column, full D.
__global__ __launch_bounds__(256) void score_kernel(
    const float* __restrict__ q, const float* __restrict__ value,
    float* __restrict__ score, float* __restrict__ invn,
    unsigned int* __restrict__ mm, int b_base)
{
    const int b   = b_base + blockIdx.y;
    const int tid = threadIdx.x;
    __shared__ float qs[D_];
    __shared__ float red[256];

    // ---- normalize q row in LDS ----
    float qv = q[b * D_ + tid];
    red[tid] = qv * qv;
    __syncthreads();
    for (int s = 128; s > 0; s >>= 1) {
        if (tid < s) red[tid] += red[tid + s];
        __syncthreads();
    }
    float qnorm2 = red[0];
    __syncthreads();
    qs[tid] = qv * (1.0f / fmaxf(sqrtf(qnorm2), 1e-12f));
    __syncthreads();

    // ---- per-thread: 2 wh columns, reduce over D ----
    const int wh0 = (blockIdx.x * 256 + tid) * 2;
    const float* vb = value + (size_t)b * D_ * WH_ + wh0;
    float ss0 = 0.f, ss1 = 0.f, dt0 = 0.f, dt1 = 0.f;
#pragma unroll 16
    for (int d = 0; d < D_; ++d) {
        float2 v2 = *(const float2*)(vb + (size_t)d * WH_);
        float qd = qs[d];
        ss0 += v2.x * v2.x; ss1 += v2.y * v2.y;
        dt0 += qd * v2.x;   dt1 += qd * v2.y;
    }
    float n0 = 1.0f / fmaxf(sqrtf(ss0), 1e-12f);
    float n1 = 1.0f / fmaxf(sqrtf(ss1), 1e-12f);
    float s0 = dt0 * n0, s1 = dt1 * n1;

    *(float2*)(score + (size_t)b * WH_ + wh0) = make_float2(s0, s1);
    *(float2*)(invn  + (size_t)b * WH_ + wh0) = make_float2(n0, n1);

    // ---- block min/max -> one atomic pair per block ----
    float mn = fminf(s0, s1);
    float mx = fmaxf(s0, s1);
    red[tid] = mn;
    __syncthreads();
    for (int s = 128; s > 0; s >>= 1) {
        if (tid < s) red[tid] = fminf(red[tid], red[tid + s]);
        __syncthreads();
    }
    float bmn = red[0];
    __syncthreads();
    red[tid] = mx;
    __syncthreads();
    for (int s = 128; s > 0; s >>= 1) {
        if (tid < s) red[tid] = fmaxf(red[tid], red[tid + s]);
        __syncthreads();
    }
    if (tid == 0) {
        atomicMin(&mm[2 * b],     fmap(bmn));
        atomicMax(&mm[2 * b + 1], fmap(red[0]));
    }
}

// grid = (32, PHB), block = 256. Each thread: one float2 wh-column, d
// descending (mirror of score within the L3-resident phase working set).
__global__ __launch_bounds__(256) void ctx_kernel(
    const float* __restrict__ value, const float* __restrict__ score,
    const float* __restrict__ invn, const unsigned int* __restrict__ mm,
    float* __restrict__ out_ctx, float* __restrict__ out_attn, int b_base)
{
    const int b   = b_base + blockIdx.y;
    const int wh0 = (blockIdx.x * 256 + threadIdx.x) * 2;

    const float mn = funmap(mm[2 * b]);
    const float sc = 1.0f / (funmap(mm[2 * b + 1]) - mn + 1e-8f);

    float2 s2 = *(const float2*)(score + (size_t)b * WH_ + wh0);
    float2 n2 = *(const float2*)(invn  + (size_t)b * WH_ + wh0);
    float a0 = (s2.x - mn) * sc;
    float a1 = (s2.y - mn) * sc;
    nt_store2(out_attn + (size_t)b * WH_ + wh0, a0, a1);

    const float an0 = a0 * n2.x, an1 = a1 * n2.y;

    const float* vb = value   + (size_t)b * D_ * WH_ + wh0;
    float*       cb = out_ctx + (size_t)b * D_ * WH_ + wh0;
#pragma unroll 8
    for (int d = D_ - 1; d >= 0; --d) {
        float2 v2 = *(const float2*)(vb + (size_t)d * WH_);
        nt_store2(cb + (size_t)d * WH_, an0 * v2.x, an1 * v2.y);
    }
}

extern "C" void kernel_launch(void* const* d_in, const int* in_sizes, int n_in,
                              void* d_out, int out_size, void* d_ws, size_t ws_size,
                              hipStream_t stream) {
    const float* q     = (const float*)d_in[0];   // [16,256]
    const float* value = (const float*)d_in[1];   // [16,256,128,128]

    float* out_ctx  = (float*)d_out;                       // B*D*WH floats
    float* out_attn = out_ctx + (size_t)B_ * D_ * WH_;     // B*WH floats

    // workspace: score [B*WH] f32 | invn [B*WH] f32 | mm [2*B] u32  (~2.1 MB)
    float* score = (float*)d_ws;
    float* invn  = score + (size_t)B_ * WH_;
    unsigned int* mm = (unsigned int*)(invn + (size_t)B_ * WH_);

    hipLaunchKernelGGL(init_mm_kernel, dim3(1), dim3(64), 0, stream, mm);

    // phase 0: b in [0,8)
    hipLaunchKernelGGL(score_kernel, dim3(32, PHB), dim3(256), 0, stream,
                       q, value, score, invn, mm, 0);
    hipLaunchKernelGGL(ctx_kernel, dim3(32, PHB), dim3(256), 0, stream,
                       value, score, invn, mm, out_ctx, out_attn, 0);

    // phase 1: b in [8,16)
    hipLaunchKernelGGL(score_kernel, dim3(32, PHB), dim3(256), 0, stream,
                       q, value, score, invn, mm, PHB);
    hipLaunchKernelGGL(ctx_kernel, dim3(32, PHB), dim3(256), 0, stream,
                       value, score, invn, mm, out_ctx, out_attn, PHB);
}